// Round 12
// baseline (214.843 us; speedup 1.0000x reference)
//
#include <hip/hip_runtime.h>
#include <cstddef>

#define NB 256     // graphs
#define M 512      // nodes per graph
#define KNN 6      // neighbors
#define C 32       // channels

// ---------------------------------------------------------------------------
// ONE kernel: block = graph (1024 threads = 512 nodes x 2 channel-halves),
// phases: in-block KNN -> L1 -> L2 -> L3 -> pool -> head. (round-11 base,
// absmax 0.0.)
// Round-12 (barrier-count attack, 23 -> ~14):
//  (1) layers 2/3 aggregate the FULL neighbor row per thread (48 reads vs 24)
//      -> h-exchange through LDS gone: 4 barriers/layer instead of 6; h values
//      bit-identical (same Ts reads, same fmax).
//  (2) pool by wave shuffle-max butterfly (registers, no barriers) + one
//      16x16 LDS handoff: replaces the 6-barrier tree with 2 barriers; max is
//      associative/commutative -> exact.
// ---------------------------------------------------------------------------
__global__ __launch_bounds__(1024, 1) void megafused_kernel(
    const float* __restrict__ x, const float* __restrict__ pos,
    const float* __restrict__ W1a, const float* __restrict__ b1a,
    const float* __restrict__ W2a, const float* __restrict__ b2a,
    const float* __restrict__ W1b, const float* __restrict__ b1b,
    const float* __restrict__ W2b, const float* __restrict__ b2b,
    const float* __restrict__ W1c, const float* __restrict__ b1c,
    const float* __restrict__ W2c, const float* __restrict__ b2c,
    const float* __restrict__ Wr,  const float* __restrict__ br,
    float* __restrict__ out)
{
    __shared__ __align__(16) float Ts[M * C];   // 64 KB, multi-purpose
    const int g  = blockIdx.x;
    const int t  = threadIdx.x;
    const int n  = t & (M - 1);                 // node 0..511
    const int hv = t >> 9;                      // 0/1, wave-uniform
    const int c0 = __builtin_amdgcn_readfirstlane(hv << 4); // SGPR weight base

    // ---- overlay for KNN phase (within the 64 KB of Ts) ----
    float4* sp          = (float4*)Ts;                          // [0, 8K) B
    float*  cd          = Ts + 2048;                            // [8K, 36K) B, stride 7
    unsigned short* ci  = (unsigned short*)(Ts + 2048 + 7168);  // [36K, 50K) B

    // === phase 0: positions + squared norms into LDS ===
    const float* p = pos + (size_t)g * M * 3;
    if (t < M) {
        float xx = p[3*t], yy = p[3*t+1], zz = p[3*t+2];
        sp[t] = make_float4(xx, yy, zz, fmaf(xx, xx, fmaf(yy, yy, zz * zz)));
    }
    __syncthreads();

    const float4 pm = sp[n];

    // === phase 1: KNN scan — row n, cols [hv*256, hv*256+256) ===
    float d0 = INFINITY, d1 = INFINITY, d2 = INFINITY,
          d3 = INFINITY, d4 = INFINITY, d5 = INFINITY;
    int   i0 = -1, i1 = -1, i2 = -1, i3 = -1, i4 = -1, i5 = -1;

    const int col0 = hv << 8;
#pragma unroll 4
    for (int jj = 0; jj < 256; jj++) {
        const int col = col0 + jj;
        const float4 pn = sp[col];                       // wave-uniform broadcast
        float dot  = fmaf(pm.x, pn.x, fmaf(pm.y, pn.y, pm.z * pn.z));
        float dist = fmaf(-2.f, dot, pm.w + pn.w);       // validated rounding chain
        // compares on OLD d values (strict < => lowest index wins on ties)
        bool c5 = dist < d5, c4 = dist < d4, c3 = dist < d3,
             c2 = dist < d2, c1 = dist < d1, cz = dist < d0;
        i5 = c4 ? i4 : (c5 ? col : i5);
        i4 = c3 ? i3 : (c4 ? col : i4);
        i3 = c2 ? i2 : (c3 ? col : i3);
        i2 = c1 ? i1 : (c2 ? col : i2);
        i1 = cz ? i0 : (c1 ? col : i1);
        i0 = cz ? col : i0;
        d5 = __builtin_amdgcn_fmed3f(dist, d4, d5);
        d4 = __builtin_amdgcn_fmed3f(dist, d3, d4);
        d3 = __builtin_amdgcn_fmed3f(dist, d2, d3);
        d2 = __builtin_amdgcn_fmed3f(dist, d1, d2);
        d1 = __builtin_amdgcn_fmed3f(dist, d0, d1);
        d0 = fminf(dist, d0);
    }
    {
        float* cdp = cd + t * 7;
        cdp[0]=d0; cdp[1]=d1; cdp[2]=d2; cdp[3]=d3; cdp[4]=d4; cdp[5]=d5;
        unsigned short* cip = ci + t * 7;
        cip[0]=(unsigned short)i0; cip[1]=(unsigned short)i1;
        cip[2]=(unsigned short)i2; cip[3]=(unsigned short)i3;
        cip[4]=(unsigned short)i4; cip[5]=(unsigned short)i5;
    }
    __syncthreads();

    // === phase 2: merge the two 6-lists (ascending halves -> tie-stable) ===
    int j[KNN];
    {
        float md[KNN]; int mi[KNN];
#pragma unroll
        for (int k = 0; k < KNN; k++) { md[k] = cd[n*7 + k]; mi[k] = ci[n*7 + k]; }
        const int L1 = (n + M) * 7;
#pragma unroll
        for (int k = 0; k < KNN; k++) {
            float dist = cd[L1 + k];
            int   nn   = ci[L1 + k];
            bool c5 = dist < md[5], c4 = dist < md[4], c3 = dist < md[3],
                 c2 = dist < md[2], c1 = dist < md[1], cz = dist < md[0];
            mi[5] = c4 ? mi[4] : (c5 ? nn : mi[5]);
            mi[4] = c3 ? mi[3] : (c4 ? nn : mi[4]);
            mi[3] = c2 ? mi[2] : (c3 ? nn : mi[3]);
            mi[2] = c1 ? mi[1] : (c2 ? nn : mi[2]);
            mi[1] = cz ? mi[0] : (c1 ? nn : mi[1]);
            mi[0] = cz ? nn : mi[0];
            md[5] = __builtin_amdgcn_fmed3f(dist, md[4], md[5]);
            md[4] = __builtin_amdgcn_fmed3f(dist, md[3], md[4]);
            md[3] = __builtin_amdgcn_fmed3f(dist, md[2], md[3]);
            md[2] = __builtin_amdgcn_fmed3f(dist, md[1], md[2]);
            md[1] = __builtin_amdgcn_fmed3f(dist, md[0], md[1]);
            md[0] = fminf(dist, md[0]);
        }
#pragma unroll
        for (int k = 0; k < KNN; k++) j[k] = mi[k];
    }
    __syncthreads();   // KNN scratch dead; Ts becomes the T-staging buffer

    const int np = n & 7;

    // === layer 1: T1 = MLP_a([x,pos]) — no gather ===
    {
        const float h0 = x[(size_t)g * M + n];
        const float h1 = pm.x, h2 = pm.y, h3 = pm.z;
        float m1[C];
#pragma unroll
        for (int o = 0; o < C; o++) {
            float a = b1a[o];
            a = fmaf(W1a[o*4+0], h0, a);
            a = fmaf(W1a[o*4+1], h1, a);
            a = fmaf(W1a[o*4+2], h2, a);
            a = fmaf(W1a[o*4+3], h3, a);
            m1[o] = fmaxf(a, 0.f);
        }
#pragma unroll
        for (int q2 = 0; q2 < 4; q2++) {
            float4 v; float* vp = &v.x;
#pragma unroll
            for (int u = 0; u < 4; u++) {
                const int o = c0 + q2*4 + u;
                float a = b2a[o];
#pragma unroll
                for (int i = 0; i < C; i++) a = fmaf(W2a[o*C + i], m1[i], a);
                vp[u] = a;
            }
            const int q = 4*hv + q2;
            *(float4*)&Ts[n*C + ((q ^ np) << 2)] = v;
        }
    }
    __syncthreads();

    // === layers 2,3: 4 barriers each (full-row agg kills the h-exchange) ===
#pragma unroll 1
    for (int layer = 0; layer < 2; layer++) {
        const float* W1 = layer ? W1c : W1b;
        const float* b1 = layer ? b1c : b1b;
        const float* W2 = layer ? W2c : W2b;
        const float* b2 = layer ? b2c : b2b;

        // A: FULL-row aggregation; 0-init folds the relu (exact)
        float hf[C];
#pragma unroll
        for (int u = 0; u < C; u++) hf[u] = 0.f;
#pragma unroll
        for (int k = 0; k < KNN; k++) {
            const int jl = j[k], jp = jl & 7;
#pragma unroll
            for (int q = 0; q < 8; q++) {
                const float4 v = *(const float4*)&Ts[jl*C + ((q ^ jp) << 2)];
                hf[4*q+0] = fmaxf(hf[4*q+0], v.x);
                hf[4*q+1] = fmaxf(hf[4*q+1], v.y);
                hf[4*q+2] = fmaxf(hf[4*q+2], v.z);
                hf[4*q+3] = fmaxf(hf[4*q+3], v.w);
            }
        }
        __syncthreads();              // all T reads done
        // D: m1 half (16 outs x 32 ins) from registers
        float m1h[16];
#pragma unroll
        for (int o2 = 0; o2 < 16; o2++) {
            const int o = c0 + o2;
            float a = b1[o];
#pragma unroll
            for (int i = 0; i < C; i++) a = fmaf(W1[o*C + i], hf[i], a);
            m1h[o2] = fmaxf(a, 0.f);
        }
#pragma unroll
        for (int q2 = 0; q2 < 4; q2++) {
            const int q = 4*hv + q2;
            *(float4*)&Ts[n*C + ((q ^ np) << 2)] =
                make_float4(m1h[4*q2], m1h[4*q2+1], m1h[4*q2+2], m1h[4*q2+3]);
        }
        __syncthreads();              // m1 visible
        // E: read full m1 row
        float m1[C];
#pragma unroll
        for (int q = 0; q < 8; q++) {
            const float4 v = *(const float4*)&Ts[n*C + ((q ^ np) << 2)];
            m1[4*q+0] = v.x; m1[4*q+1] = v.y; m1[4*q+2] = v.z; m1[4*q+3] = v.w;
        }
        __syncthreads();              // m1 reads done (T write aliases)
        // F: T half-row
#pragma unroll
        for (int q2 = 0; q2 < 4; q2++) {
            float4 v; float* vp = &v.x;
#pragma unroll
            for (int u = 0; u < 4; u++) {
                const int o = c0 + q2*4 + u;
                float a = b2[o];
#pragma unroll
                for (int i = 0; i < C; i++) a = fmaf(W2[o*C + i], m1[i], a);
                vp[u] = a;
            }
            const int q = 4*hv + q2;
            *(float4*)&Ts[n*C + ((q ^ np) << 2)] = v;
        }
        __syncthreads();              // T visible
    }

    // === final aggregation (h3, half-row) + pool via wave shuffle-max ===
    {
        float hm[16];
#pragma unroll
        for (int u = 0; u < 16; u++) hm[u] = 0.f;   // relu fold (exact)
#pragma unroll
        for (int k = 0; k < KNN; k++) {
            const int jl = j[k], jp = jl & 7;
#pragma unroll
            for (int q2 = 0; q2 < 4; q2++) {
                const int q = 4*hv + q2;
                const float4 v = *(const float4*)&Ts[jl*C + ((q ^ jp) << 2)];
                hm[4*q2+0] = fmaxf(hm[4*q2+0], v.x);
                hm[4*q2+1] = fmaxf(hm[4*q2+1], v.y);
                hm[4*q2+2] = fmaxf(hm[4*q2+2], v.z);
                hm[4*q2+3] = fmaxf(hm[4*q2+3], v.w);
            }
        }
        // butterfly max over the wave's 64 nodes (registers only; exact)
#pragma unroll
        for (int off = 32; off >= 1; off >>= 1) {
#pragma unroll
            for (int u = 0; u < 16; u++)
                hm[u] = fmaxf(hm[u], __shfl_xor(hm[u], off, 64));
        }
        __syncthreads();              // all T3 reads done; Ts reusable
        if ((t & 63) == 0) {          // one lane per wave: Wred[wave][16]
            const int w = t >> 6;
#pragma unroll
            for (int q2 = 0; q2 < 4; q2++)
                *(float4*)&Ts[w*16 + 4*q2] =
                    make_float4(hm[4*q2], hm[4*q2+1], hm[4*q2+2], hm[4*q2+3]);
        }
        __syncthreads();              // Wred visible
    }

    // wave 0 finishes: gmax (32 ch) then head; same-wave program order => no
    // further barriers needed (LDS waits are compiler-inserted lgkmcnt)
    if (t < 32) {
        const int c  = t & 15;
        const int w0 = (t >> 4) << 3;    // channels 0-15 from waves 0-7, 16-31 from 8-15
        float m = 0.f;                   // h3 >= 0 post-relu
#pragma unroll
        for (int w = 0; w < 8; w++) m = fmaxf(m, Ts[(w0 + w)*16 + c]);
        Ts[256 + t] = m;
    }
    if (t < 6) {
        float a = br[t];
#pragma unroll
        for (int i = 0; i < C; i++) a = fmaf(Wr[t*C + i], Ts[256 + i], a);
        out[g * 6 + t] = a;
    }
}

extern "C" void kernel_launch(void* const* d_in, const int* in_sizes, int n_in,
                              void* d_out, int out_size, void* d_ws, size_t ws_size,
                              hipStream_t stream) {
    const float* x   = (const float*)d_in[0];
    const float* pos = (const float*)d_in[1];
    // d_in[2] = batch (int64) unused: nodes are contiguous M-per-graph
    const float* W1a = (const float*)d_in[3];
    const float* b1a = (const float*)d_in[4];
    const float* W2a = (const float*)d_in[5];
    const float* b2a = (const float*)d_in[6];
    const float* W1b = (const float*)d_in[7];
    const float* b1b = (const float*)d_in[8];
    const float* W2b = (const float*)d_in[9];
    const float* b2b = (const float*)d_in[10];
    const float* W1c = (const float*)d_in[11];
    const float* b1c = (const float*)d_in[12];
    const float* W2c = (const float*)d_in[13];
    const float* b2c = (const float*)d_in[14];
    const float* Wr  = (const float*)d_in[15];
    const float* br  = (const float*)d_in[16];

    float* out = (float*)d_out;

    megafused_kernel<<<NB, 1024, 0, stream>>>(x, pos,
                                              W1a, b1a, W2a, b2a,
                                              W1b, b1b, W2b, b2b,
                                              W1c, b1c, W2c, b2c,
                                              Wr, br, out);
}

// Round 13
// 189.234 us; speedup vs baseline: 1.1353x; 1.1353x over previous
//
#include <hip/hip_runtime.h>
#include <cstddef>

#define NB 256     // graphs
#define M 512      // nodes per graph
#define KNN 6      // neighbors
#define C 32       // channels

// ---------------------------------------------------------------------------
// ONE kernel: block = graph (1024 threads = 512 nodes x 2 channel-halves),
// phases: in-block KNN -> L1 -> L2 -> L3 -> pool -> head.
// Round-13 = round-11 base (validated 108us, VGPR 60, no spills) + round-12's
// validated shuffle-max pool ONLY. Round-12's full-row aggregation is
// REVERTED: it pushed live state past the 64-VGPR granule for 1024-thread
// blocks -> 48 MB scratch spill traffic (FETCH 16.9 MB, WRITE 29.7 MB).
// RULE: keep natural VGPR <= 64 for this block size.
// ---------------------------------------------------------------------------
__global__ __launch_bounds__(1024, 1) void megafused_kernel(
    const float* __restrict__ x, const float* __restrict__ pos,
    const float* __restrict__ W1a, const float* __restrict__ b1a,
    const float* __restrict__ W2a, const float* __restrict__ b2a,
    const float* __restrict__ W1b, const float* __restrict__ b1b,
    const float* __restrict__ W2b, const float* __restrict__ b2b,
    const float* __restrict__ W1c, const float* __restrict__ b1c,
    const float* __restrict__ W2c, const float* __restrict__ b2c,
    const float* __restrict__ Wr,  const float* __restrict__ br,
    float* __restrict__ out)
{
    __shared__ __align__(16) float Ts[M * C];   // 64 KB, multi-purpose
    const int g  = blockIdx.x;
    const int t  = threadIdx.x;
    const int n  = t & (M - 1);                 // node 0..511
    const int hv = t >> 9;                      // 0/1, wave-uniform
    const int c0 = __builtin_amdgcn_readfirstlane(hv << 4); // SGPR weight base

    // ---- overlay for KNN phase (within the 64 KB of Ts) ----
    float4* sp          = (float4*)Ts;                          // [0, 8K) B
    float*  cd          = Ts + 2048;                            // [8K, 36K) B, stride 7
    unsigned short* ci  = (unsigned short*)(Ts + 2048 + 7168);  // [36K, 50K) B

    // === phase 0: positions + squared norms into LDS ===
    const float* p = pos + (size_t)g * M * 3;
    if (t < M) {
        float xx = p[3*t], yy = p[3*t+1], zz = p[3*t+2];
        sp[t] = make_float4(xx, yy, zz, fmaf(xx, xx, fmaf(yy, yy, zz * zz)));
    }
    __syncthreads();

    const float4 pm = sp[n];

    // === phase 1: KNN scan — row n, cols [hv*256, hv*256+256) ===
    float d0 = INFINITY, d1 = INFINITY, d2 = INFINITY,
          d3 = INFINITY, d4 = INFINITY, d5 = INFINITY;
    int   i0 = -1, i1 = -1, i2 = -1, i3 = -1, i4 = -1, i5 = -1;

    const int col0 = hv << 8;
#pragma unroll 4
    for (int jj = 0; jj < 256; jj++) {
        const int col = col0 + jj;
        const float4 pn = sp[col];                       // wave-uniform broadcast
        float dot  = fmaf(pm.x, pn.x, fmaf(pm.y, pn.y, pm.z * pn.z));
        float dist = fmaf(-2.f, dot, pm.w + pn.w);       // validated rounding chain
        // compares on OLD d values (strict < => lowest index wins on ties)
        bool c5 = dist < d5, c4 = dist < d4, c3 = dist < d3,
             c2 = dist < d2, c1 = dist < d1, cz = dist < d0;
        i5 = c4 ? i4 : (c5 ? col : i5);
        i4 = c3 ? i3 : (c4 ? col : i4);
        i3 = c2 ? i2 : (c3 ? col : i3);
        i2 = c1 ? i1 : (c2 ? col : i2);
        i1 = cz ? i0 : (c1 ? col : i1);
        i0 = cz ? col : i0;
        d5 = __builtin_amdgcn_fmed3f(dist, d4, d5);
        d4 = __builtin_amdgcn_fmed3f(dist, d3, d4);
        d3 = __builtin_amdgcn_fmed3f(dist, d2, d3);
        d2 = __builtin_amdgcn_fmed3f(dist, d1, d2);
        d1 = __builtin_amdgcn_fmed3f(dist, d0, d1);
        d0 = fminf(dist, d0);
    }
    {
        float* cdp = cd + t * 7;
        cdp[0]=d0; cdp[1]=d1; cdp[2]=d2; cdp[3]=d3; cdp[4]=d4; cdp[5]=d5;
        unsigned short* cip = ci + t * 7;
        cip[0]=(unsigned short)i0; cip[1]=(unsigned short)i1;
        cip[2]=(unsigned short)i2; cip[3]=(unsigned short)i3;
        cip[4]=(unsigned short)i4; cip[5]=(unsigned short)i5;
    }
    __syncthreads();

    // === phase 2: merge the two 6-lists (ascending halves -> tie-stable) ===
    int j[KNN];
    {
        float md[KNN]; int mi[KNN];
#pragma unroll
        for (int k = 0; k < KNN; k++) { md[k] = cd[n*7 + k]; mi[k] = ci[n*7 + k]; }
        const int L1 = (n + M) * 7;
#pragma unroll
        for (int k = 0; k < KNN; k++) {
            float dist = cd[L1 + k];
            int   nn   = ci[L1 + k];
            bool c5 = dist < md[5], c4 = dist < md[4], c3 = dist < md[3],
                 c2 = dist < md[2], c1 = dist < md[1], cz = dist < md[0];
            mi[5] = c4 ? mi[4] : (c5 ? nn : mi[5]);
            mi[4] = c3 ? mi[3] : (c4 ? nn : mi[4]);
            mi[3] = c2 ? mi[2] : (c3 ? nn : mi[3]);
            mi[2] = c1 ? mi[1] : (c2 ? nn : mi[2]);
            mi[1] = cz ? mi[0] : (c1 ? nn : mi[1]);
            mi[0] = cz ? nn : mi[0];
            md[5] = __builtin_amdgcn_fmed3f(dist, md[4], md[5]);
            md[4] = __builtin_amdgcn_fmed3f(dist, md[3], md[4]);
            md[3] = __builtin_amdgcn_fmed3f(dist, md[2], md[3]);
            md[2] = __builtin_amdgcn_fmed3f(dist, md[1], md[2]);
            md[1] = __builtin_amdgcn_fmed3f(dist, md[0], md[1]);
            md[0] = fminf(dist, md[0]);
        }
#pragma unroll
        for (int k = 0; k < KNN; k++) j[k] = mi[k];
    }
    __syncthreads();   // KNN scratch dead; Ts becomes the T-staging buffer

    const int np = n & 7;

    // === layer 1: T1 = MLP_a([x,pos]) — no gather ===
    {
        const float h0 = x[(size_t)g * M + n];
        const float h1 = pm.x, h2 = pm.y, h3 = pm.z;
        float m1[C];
#pragma unroll
        for (int o = 0; o < C; o++) {
            float a = b1a[o];
            a = fmaf(W1a[o*4+0], h0, a);
            a = fmaf(W1a[o*4+1], h1, a);
            a = fmaf(W1a[o*4+2], h2, a);
            a = fmaf(W1a[o*4+3], h3, a);
            m1[o] = fmaxf(a, 0.f);
        }
#pragma unroll
        for (int q2 = 0; q2 < 4; q2++) {
            float4 v; float* vp = &v.x;
#pragma unroll
            for (int u = 0; u < 4; u++) {
                const int o = c0 + q2*4 + u;
                float a = b2a[o];
#pragma unroll
                for (int i = 0; i < C; i++) a = fmaf(W2a[o*C + i], m1[i], a);
                vp[u] = a;
            }
            const int q = 4*hv + q2;
            *(float4*)&Ts[n*C + ((q ^ np) << 2)] = v;
        }
    }
    __syncthreads();

    // === layers 2,3 (round-11 low-pressure form: half-row agg + exchanges) ===
#pragma unroll 1
    for (int layer = 0; layer < 2; layer++) {
        const float* W1 = layer ? W1c : W1b;
        const float* b1 = layer ? b1c : b1b;
        const float* W2 = layer ? W2c : W2b;
        const float* b2 = layer ? b2c : b2b;

        // A: aggregate neighbors' half-rows; 0-init folds the relu (exact)
        float hm[16];
#pragma unroll
        for (int u = 0; u < 16; u++) hm[u] = 0.f;
#pragma unroll
        for (int k = 0; k < KNN; k++) {
            const int jl = j[k], jp = jl & 7;
#pragma unroll
            for (int q2 = 0; q2 < 4; q2++) {
                const int q = 4*hv + q2;
                const float4 v = *(const float4*)&Ts[jl*C + ((q ^ jp) << 2)];
                hm[4*q2+0] = fmaxf(hm[4*q2+0], v.x);
                hm[4*q2+1] = fmaxf(hm[4*q2+1], v.y);
                hm[4*q2+2] = fmaxf(hm[4*q2+2], v.z);
                hm[4*q2+3] = fmaxf(hm[4*q2+3], v.w);
            }
        }
        __syncthreads();              // all T reads done
        // B: write h half-row (overwrites T)
#pragma unroll
        for (int q2 = 0; q2 < 4; q2++) {
            const int q = 4*hv + q2;
            *(float4*)&Ts[n*C + ((q ^ np) << 2)] =
                make_float4(hm[4*q2], hm[4*q2+1], hm[4*q2+2], hm[4*q2+3]);
        }
        __syncthreads();              // h visible
        // C: read full h row of own node
        float hf[C];
#pragma unroll
        for (int q = 0; q < 8; q++) {
            const float4 v = *(const float4*)&Ts[n*C + ((q ^ np) << 2)];
            hf[4*q+0] = v.x; hf[4*q+1] = v.y; hf[4*q+2] = v.z; hf[4*q+3] = v.w;
        }
        __syncthreads();              // h reads done (m1 write below aliases)
        // D: m1 half (16 outs x 32 ins)
        float m1h[16];
#pragma unroll
        for (int o2 = 0; o2 < 16; o2++) {
            const int o = c0 + o2;
            float a = b1[o];
#pragma unroll
            for (int i = 0; i < C; i++) a = fmaf(W1[o*C + i], hf[i], a);
            m1h[o2] = fmaxf(a, 0.f);
        }
#pragma unroll
        for (int q2 = 0; q2 < 4; q2++) {
            const int q = 4*hv + q2;
            *(float4*)&Ts[n*C + ((q ^ np) << 2)] =
                make_float4(m1h[4*q2], m1h[4*q2+1], m1h[4*q2+2], m1h[4*q2+3]);
        }
        __syncthreads();              // m1 visible
        // E: read full m1 row
        float m1[C];
#pragma unroll
        for (int q = 0; q < 8; q++) {
            const float4 v = *(const float4*)&Ts[n*C + ((q ^ np) << 2)];
            m1[4*q+0] = v.x; m1[4*q+1] = v.y; m1[4*q+2] = v.z; m1[4*q+3] = v.w;
        }
        __syncthreads();              // m1 reads done (T write aliases)
        // F: T half-row
#pragma unroll
        for (int q2 = 0; q2 < 4; q2++) {
            float4 v; float* vp = &v.x;
#pragma unroll
            for (int u = 0; u < 4; u++) {
                const int o = c0 + q2*4 + u;
                float a = b2[o];
#pragma unroll
                for (int i = 0; i < C; i++) a = fmaf(W2[o*C + i], m1[i], a);
                vp[u] = a;
            }
            const int q = 4*hv + q2;
            *(float4*)&Ts[n*C + ((q ^ np) << 2)] = v;
        }
        __syncthreads();              // T visible
    }

    // === final aggregation (h3, half-row) + pool via wave shuffle-max ===
    // (round-12 validated: max is associative/commutative -> exact)
    {
        float hm[16];
#pragma unroll
        for (int u = 0; u < 16; u++) hm[u] = 0.f;   // relu fold (exact)
#pragma unroll
        for (int k = 0; k < KNN; k++) {
            const int jl = j[k], jp = jl & 7;
#pragma unroll
            for (int q2 = 0; q2 < 4; q2++) {
                const int q = 4*hv + q2;
                const float4 v = *(const float4*)&Ts[jl*C + ((q ^ jp) << 2)];
                hm[4*q2+0] = fmaxf(hm[4*q2+0], v.x);
                hm[4*q2+1] = fmaxf(hm[4*q2+1], v.y);
                hm[4*q2+2] = fmaxf(hm[4*q2+2], v.z);
                hm[4*q2+3] = fmaxf(hm[4*q2+3], v.w);
            }
        }
        // butterfly max over the wave's 64 nodes (registers only; exact)
#pragma unroll
        for (int off = 32; off >= 1; off >>= 1) {
#pragma unroll
            for (int u = 0; u < 16; u++)
                hm[u] = fmaxf(hm[u], __shfl_xor(hm[u], off, 64));
        }
        __syncthreads();              // all T3 reads done; Ts reusable
        if ((t & 63) == 0) {          // one lane per wave: Wred[wave][16]
            const int w = t >> 6;
#pragma unroll
            for (int q2 = 0; q2 < 4; q2++)
                *(float4*)&Ts[w*16 + 4*q2] =
                    make_float4(hm[4*q2], hm[4*q2+1], hm[4*q2+2], hm[4*q2+3]);
        }
        __syncthreads();              // Wred visible
    }

    // wave 0 finishes: gmax (32 ch) then head; same-wave program order => no
    // further barriers needed (LDS waits are compiler-inserted lgkmcnt)
    if (t < 32) {
        const int c  = t & 15;
        const int w0 = (t >> 4) << 3;    // ch 0-15 from waves 0-7; 16-31 from 8-15
        float m = 0.f;                   // h3 >= 0 post-relu
#pragma unroll
        for (int w = 0; w < 8; w++) m = fmaxf(m, Ts[(w0 + w)*16 + c]);
        Ts[256 + t] = m;
    }
    if (t < 6) {
        float a = br[t];
#pragma unroll
        for (int i = 0; i < C; i++) a = fmaf(Wr[t*C + i], Ts[256 + i], a);
        out[g * 6 + t] = a;
    }
}

extern "C" void kernel_launch(void* const* d_in, const int* in_sizes, int n_in,
                              void* d_out, int out_size, void* d_ws, size_t ws_size,
                              hipStream_t stream) {
    const float* x   = (const float*)d_in[0];
    const float* pos = (const float*)d_in[1];
    // d_in[2] = batch (int64) unused: nodes are contiguous M-per-graph
    const float* W1a = (const float*)d_in[3];
    const float* b1a = (const float*)d_in[4];
    const float* W2a = (const float*)d_in[5];
    const float* b2a = (const float*)d_in[6];
    const float* W1b = (const float*)d_in[7];
    const float* b1b = (const float*)d_in[8];
    const float* W2b = (const float*)d_in[9];
    const float* b2b = (const float*)d_in[10];
    const float* W1c = (const float*)d_in[11];
    const float* b1c = (const float*)d_in[12];
    const float* W2c = (const float*)d_in[13];
    const float* b2c = (const float*)d_in[14];
    const float* Wr  = (const float*)d_in[15];
    const float* br  = (const float*)d_in[16];

    float* out = (float*)d_out;

    megafused_kernel<<<NB, 1024, 0, stream>>>(x, pos,
                                              W1a, b1a, W2a, b2a,
                                              W1b, b1b, W2b, b2b,
                                              W1c, b1c, W2c, b2c,
                                              Wr, br, out);
}

// Round 14
// 181.307 us; speedup vs baseline: 1.1850x; 1.0437x over previous
//
#include <hip/hip_runtime.h>
#include <cstddef>

#define NB 256     // graphs
#define M 512      // nodes per graph
#define KNN 6      // neighbors
#define C 32       // channels

// ---------------------------------------------------------------------------
// ONE kernel: block = graph (1024 threads = 512 nodes x 2 channel-halves),
// phases: in-block KNN -> L1 -> L2 -> L3 -> pool -> head.
// Round-14 = round-11 arithmetic EXACTLY (bit-identical outputs; round 11 is
// the best measured config) with LDS ping-pong: TsA+TsB = 128 KB of the CU's
// 160 KB. A-phase reads T_prev while all exchange/T writes hit T_cur ->
// removes the alias barriers (6 -> 5 per layer, plus 2 more elsewhere).
// Round-13 lesson: shuffle-pool costs more than the tree it replaced ->
// round-11 tree tail retained. RULE kept: natural VGPR <= 64 @ 1024 thr.
// ---------------------------------------------------------------------------
__global__ __launch_bounds__(1024, 1) void megafused_kernel(
    const float* __restrict__ x, const float* __restrict__ pos,
    const float* __restrict__ W1a, const float* __restrict__ b1a,
    const float* __restrict__ W2a, const float* __restrict__ b2a,
    const float* __restrict__ W1b, const float* __restrict__ b1b,
    const float* __restrict__ W2b, const float* __restrict__ b2b,
    const float* __restrict__ W1c, const float* __restrict__ b1c,
    const float* __restrict__ W2c, const float* __restrict__ b2c,
    const float* __restrict__ Wr,  const float* __restrict__ br,
    float* __restrict__ out)
{
    __shared__ __align__(16) float TsA[M * C];   // 64 KB
    __shared__ __align__(16) float TsB[M * C];   // 64 KB
    const int g  = blockIdx.x;
    const int t  = threadIdx.x;
    const int n  = t & (M - 1);                 // node 0..511
    const int hv = t >> 9;                      // 0/1, wave-uniform
    const int c0 = __builtin_amdgcn_readfirstlane(hv << 4); // SGPR weight base

    // ---- KNN scratch overlays TsA (dead before first TsA T-use) ----
    float4* sp          = (float4*)TsA;                          // [0, 8K) B
    float*  cd          = TsA + 2048;                            // [8K,36K) B, stride 7
    unsigned short* ci  = (unsigned short*)(TsA + 2048 + 7168);  // [36K,50K) B

    // === phase 0: positions + squared norms into LDS ===
    const float* p = pos + (size_t)g * M * 3;
    if (t < M) {
        float xx = p[3*t], yy = p[3*t+1], zz = p[3*t+2];
        sp[t] = make_float4(xx, yy, zz, fmaf(xx, xx, fmaf(yy, yy, zz * zz)));
    }
    __syncthreads();

    const float4 pm = sp[n];

    // === phase 1: KNN scan — row n, cols [hv*256, hv*256+256) ===
    float d0 = INFINITY, d1 = INFINITY, d2 = INFINITY,
          d3 = INFINITY, d4 = INFINITY, d5 = INFINITY;
    int   i0 = -1, i1 = -1, i2 = -1, i3 = -1, i4 = -1, i5 = -1;

    const int col0 = hv << 8;
#pragma unroll 4
    for (int jj = 0; jj < 256; jj++) {
        const int col = col0 + jj;
        const float4 pn = sp[col];                       // wave-uniform broadcast
        float dot  = fmaf(pm.x, pn.x, fmaf(pm.y, pn.y, pm.z * pn.z));
        float dist = fmaf(-2.f, dot, pm.w + pn.w);       // validated rounding chain
        // compares on OLD d values (strict < => lowest index wins on ties)
        bool c5 = dist < d5, c4 = dist < d4, c3 = dist < d3,
             c2 = dist < d2, c1 = dist < d1, cz = dist < d0;
        i5 = c4 ? i4 : (c5 ? col : i5);
        i4 = c3 ? i3 : (c4 ? col : i4);
        i3 = c2 ? i2 : (c3 ? col : i3);
        i2 = c1 ? i1 : (c2 ? col : i2);
        i1 = cz ? i0 : (c1 ? col : i1);
        i0 = cz ? col : i0;
        d5 = __builtin_amdgcn_fmed3f(dist, d4, d5);
        d4 = __builtin_amdgcn_fmed3f(dist, d3, d4);
        d3 = __builtin_amdgcn_fmed3f(dist, d2, d3);
        d2 = __builtin_amdgcn_fmed3f(dist, d1, d2);
        d1 = __builtin_amdgcn_fmed3f(dist, d0, d1);
        d0 = fminf(dist, d0);
    }
    {
        float* cdp = cd + t * 7;
        cdp[0]=d0; cdp[1]=d1; cdp[2]=d2; cdp[3]=d3; cdp[4]=d4; cdp[5]=d5;
        unsigned short* cip = ci + t * 7;
        cip[0]=(unsigned short)i0; cip[1]=(unsigned short)i1;
        cip[2]=(unsigned short)i2; cip[3]=(unsigned short)i3;
        cip[4]=(unsigned short)i4; cip[5]=(unsigned short)i5;
    }
    __syncthreads();

    // === phase 2: merge the two 6-lists (ascending halves -> tie-stable) ===
    int j[KNN];
    {
        float md[KNN]; int mi[KNN];
#pragma unroll
        for (int k = 0; k < KNN; k++) { md[k] = cd[n*7 + k]; mi[k] = ci[n*7 + k]; }
        const int L1 = (n + M) * 7;
#pragma unroll
        for (int k = 0; k < KNN; k++) {
            float dist = cd[L1 + k];
            int   nn   = ci[L1 + k];
            bool c5 = dist < md[5], c4 = dist < md[4], c3 = dist < md[3],
                 c2 = dist < md[2], c1 = dist < md[1], cz = dist < md[0];
            mi[5] = c4 ? mi[4] : (c5 ? nn : mi[5]);
            mi[4] = c3 ? mi[3] : (c4 ? nn : mi[4]);
            mi[3] = c2 ? mi[2] : (c3 ? nn : mi[3]);
            mi[2] = c1 ? mi[1] : (c2 ? nn : mi[2]);
            mi[1] = cz ? mi[0] : (c1 ? nn : mi[1]);
            mi[0] = cz ? nn : mi[0];
            md[5] = __builtin_amdgcn_fmed3f(dist, md[4], md[5]);
            md[4] = __builtin_amdgcn_fmed3f(dist, md[3], md[4]);
            md[3] = __builtin_amdgcn_fmed3f(dist, md[2], md[3]);
            md[2] = __builtin_amdgcn_fmed3f(dist, md[1], md[2]);
            md[1] = __builtin_amdgcn_fmed3f(dist, md[0], md[1]);
            md[0] = fminf(dist, md[0]);
        }
#pragma unroll
        for (int k = 0; k < KNN; k++) j[k] = mi[k];
    }
    // NO barrier: layer-1 writes TsB; KNN scratch (TsA) reads complete per-thread

    const int np = n & 7;

    // === layer 1: T1 = MLP_a([x,pos]) -> TsB ===
    {
        const float h0 = x[(size_t)g * M + n];
        const float h1 = pm.x, h2 = pm.y, h3 = pm.z;
        float m1[C];
#pragma unroll
        for (int o = 0; o < C; o++) {
            float a = b1a[o];
            a = fmaf(W1a[o*4+0], h0, a);
            a = fmaf(W1a[o*4+1], h1, a);
            a = fmaf(W1a[o*4+2], h2, a);
            a = fmaf(W1a[o*4+3], h3, a);
            m1[o] = fmaxf(a, 0.f);
        }
#pragma unroll
        for (int q2 = 0; q2 < 4; q2++) {
            float4 v; float* vp = &v.x;
#pragma unroll
            for (int u = 0; u < 4; u++) {
                const int o = c0 + q2*4 + u;
                float a = b2a[o];
#pragma unroll
                for (int i = 0; i < C; i++) a = fmaf(W2a[o*C + i], m1[i], a);
                vp[u] = a;
            }
            const int q = 4*hv + q2;
            *(float4*)&TsB[n*C + ((q ^ np) << 2)] = v;
        }
    }
    __syncthreads();   // T1 visible (also orders all sp/cd/ci reads before reuse)

    // === layers 2,3: ping-pong, 5 barriers each ===
#pragma unroll 1
    for (int layer = 0; layer < 2; layer++) {
        const float* W1 = layer ? W1c : W1b;
        const float* b1 = layer ? b1c : b1b;
        const float* W2 = layer ? W2c : W2b;
        const float* b2 = layer ? b2c : b2b;
        float* Tp = layer ? TsA : TsB;    // previous layer's T
        float* Tc = layer ? TsB : TsA;    // this layer's staging + T

        // A: aggregate neighbors' half-rows from Tp; 0-init folds relu (exact)
        float hm[16];
#pragma unroll
        for (int u = 0; u < 16; u++) hm[u] = 0.f;
#pragma unroll
        for (int k = 0; k < KNN; k++) {
            const int jl = j[k], jp = jl & 7;
#pragma unroll
            for (int q2 = 0; q2 < 4; q2++) {
                const int q = 4*hv + q2;
                const float4 v = *(const float4*)&Tp[jl*C + ((q ^ jp) << 2)];
                hm[4*q2+0] = fmaxf(hm[4*q2+0], v.x);
                hm[4*q2+1] = fmaxf(hm[4*q2+1], v.y);
                hm[4*q2+2] = fmaxf(hm[4*q2+2], v.z);
                hm[4*q2+3] = fmaxf(hm[4*q2+3], v.w);
            }
        }
        // B: write h half-row into Tc (no alias with A's Tp reads -> no barrier)
#pragma unroll
        for (int q2 = 0; q2 < 4; q2++) {
            const int q = 4*hv + q2;
            *(float4*)&Tc[n*C + ((q ^ np) << 2)] =
                make_float4(hm[4*q2], hm[4*q2+1], hm[4*q2+2], hm[4*q2+3]);
        }
        __syncthreads();              // h visible
        // C: read full h row of own node
        float hf[C];
#pragma unroll
        for (int q = 0; q < 8; q++) {
            const float4 v = *(const float4*)&Tc[n*C + ((q ^ np) << 2)];
            hf[4*q+0] = v.x; hf[4*q+1] = v.y; hf[4*q+2] = v.z; hf[4*q+3] = v.w;
        }
        __syncthreads();              // h reads done (m1 write below aliases)
        // D: m1 half (16 outs x 32 ins)
        float m1h[16];
#pragma unroll
        for (int o2 = 0; o2 < 16; o2++) {
            const int o = c0 + o2;
            float a = b1[o];
#pragma unroll
            for (int i = 0; i < C; i++) a = fmaf(W1[o*C + i], hf[i], a);
            m1h[o2] = fmaxf(a, 0.f);
        }
#pragma unroll
        for (int q2 = 0; q2 < 4; q2++) {
            const int q = 4*hv + q2;
            *(float4*)&Tc[n*C + ((q ^ np) << 2)] =
                make_float4(m1h[4*q2], m1h[4*q2+1], m1h[4*q2+2], m1h[4*q2+3]);
        }
        __syncthreads();              // m1 visible
        // E: read full m1 row
        float m1[C];
#pragma unroll
        for (int q = 0; q < 8; q++) {
            const float4 v = *(const float4*)&Tc[n*C + ((q ^ np) << 2)];
            m1[4*q+0] = v.x; m1[4*q+1] = v.y; m1[4*q+2] = v.z; m1[4*q+3] = v.w;
        }
        __syncthreads();              // m1 reads done (T write aliases)
        // F: T half-row -> Tc
#pragma unroll
        for (int q2 = 0; q2 < 4; q2++) {
            float4 v; float* vp = &v.x;
#pragma unroll
            for (int u = 0; u < 4; u++) {
                const int o = c0 + q2*4 + u;
                float a = b2[o];
#pragma unroll
                for (int i = 0; i < C; i++) a = fmaf(W2[o*C + i], m1[i], a);
                vp[u] = a;
            }
            const int q = 4*hv + q2;
            *(float4*)&Tc[n*C + ((q ^ np) << 2)] = v;
        }
        __syncthreads();              // T visible
    }
    // T3 now lives in TsB

    // === final aggregation (h3, half-row) -> TsA (no alias with TsB reads) ===
    {
        float hm[16];
#pragma unroll
        for (int u = 0; u < 16; u++) hm[u] = 0.f;   // relu fold (exact)
#pragma unroll
        for (int k = 0; k < KNN; k++) {
            const int jl = j[k], jp = jl & 7;
#pragma unroll
            for (int q2 = 0; q2 < 4; q2++) {
                const int q = 4*hv + q2;
                const float4 v = *(const float4*)&TsB[jl*C + ((q ^ jp) << 2)];
                hm[4*q2+0] = fmaxf(hm[4*q2+0], v.x);
                hm[4*q2+1] = fmaxf(hm[4*q2+1], v.y);
                hm[4*q2+2] = fmaxf(hm[4*q2+2], v.z);
                hm[4*q2+3] = fmaxf(hm[4*q2+3], v.w);
            }
        }
#pragma unroll
        for (int q2 = 0; q2 < 4; q2++) {
            const int q = 4*hv + q2;
            *(float4*)&TsA[n*C + ((q ^ np) << 2)] =
                make_float4(hm[4*q2], hm[4*q2+1], hm[4*q2+2], hm[4*q2+3]);
        }
        __syncthreads();              // h3 visible
    }

    // === global max pool: tree reduce rows 512 -> 32 on TsA (round-11 tail) ===
    const int tp = t & 7;
    for (int s = 256; s >= 32; s >>= 1) {
        if (t < s) {
#pragma unroll
            for (int q = 0; q < 8; q++) {
                const int ph = (q ^ tp) << 2;
                float4 a = *(const float4*)&TsA[t*C + ph];
                float4 b = *(const float4*)&TsA[(t + s)*C + ph];
                a.x = fmaxf(a.x, b.x); a.y = fmaxf(a.y, b.y);
                a.z = fmaxf(a.z, b.z); a.w = fmaxf(a.w, b.w);
                *(float4*)&TsA[t*C + ph] = a;
            }
        }
        __syncthreads();
    }

    if (t < C) {   // wave 0: reduce final 32 rows (reads precede write in-wave)
        float m = -INFINITY;
#pragma unroll
        for (int r = 0; r < 32; r++)
            m = fmaxf(m, TsA[r*C + ((((t >> 2) ^ (r & 7)) << 2) | (t & 3))]);
        TsA[t] = m;
    }
    __syncthreads();

    if (t < 6) {
        float a = br[t];
#pragma unroll
        for (int i = 0; i < C; i++) a = fmaf(Wr[t*C + i], TsA[i], a);
        out[g * 6 + t] = a;
    }
}

extern "C" void kernel_launch(void* const* d_in, const int* in_sizes, int n_in,
                              void* d_out, int out_size, void* d_ws, size_t ws_size,
                              hipStream_t stream) {
    const float* x   = (const float*)d_in[0];
    const float* pos = (const float*)d_in[1];
    // d_in[2] = batch (int64) unused: nodes are contiguous M-per-graph
    const float* W1a = (const float*)d_in[3];
    const float* b1a = (const float*)d_in[4];
    const float* W2a = (const float*)d_in[5];
    const float* b2a = (const float*)d_in[6];
    const float* W1b = (const float*)d_in[7];
    const float* b1b = (const float*)d_in[8];
    const float* W2b = (const float*)d_in[9];
    const float* b2b = (const float*)d_in[10];
    const float* W1c = (const float*)d_in[11];
    const float* b1c = (const float*)d_in[12];
    const float* W2c = (const float*)d_in[13];
    const float* b2c = (const float*)d_in[14];
    const float* Wr  = (const float*)d_in[15];
    const float* br  = (const float*)d_in[16];

    float* out = (float*)d_out;

    megafused_kernel<<<NB, 1024, 0, stream>>>(x, pos,
                                              W1a, b1a, W2a, b2a,
                                              W1b, b1b, W2b, b2b,
                                              W1c, b1c, W2c, b2c,
                                              Wr, br, out);
}